// Round 1
// baseline (396.598 us; speedup 1.0000x reference)
//
#include <hip/hip_runtime.h>
#include <hip/hip_bf16.h>
#include <math.h>

#define T_TOK 4096
#define D_EMB 768
#define DFF   3072
#define N_EXP 8

typedef __attribute__((ext_vector_type(8))) short bf16x8;
typedef __attribute__((ext_vector_type(4))) float f32x4;

typedef __attribute__((address_space(3))) unsigned int lds_u32_t;
typedef __attribute__((address_space(1))) unsigned int glob_u32_t;

__device__ __forceinline__ void gload16(const void* g, void* l) {
  __builtin_amdgcn_global_load_lds((const glob_u32_t*)g, (lds_u32_t*)l, 16, 0, 0);
}

__device__ __forceinline__ short f2bf(float f) {
  union { __hip_bfloat16 b; short s; } u;
  u.b = __float2bfloat16(f);
  return u.s;
}

// ---------------- zero out + counters ----------------
__global__ void zero_init_kernel(float4* __restrict__ out4, int n4, int* __restrict__ cnt) {
  int i = blockIdx.x * blockDim.x + threadIdx.x;
  if (i < N_EXP) cnt[i] = 0;
  float4 z; z.x = z.y = z.z = z.w = 0.f;
  for (int j = i; j < n4; j += gridDim.x * blockDim.x) out4[j] = z;
}

// ---------------- x fp32 -> bf16 ----------------
__global__ void cast_x_kernel(const float4* __restrict__ in, short4* __restrict__ outp, int n4) {
  int i = blockIdx.x * blockDim.x + threadIdx.x;
  if (i >= n4) return;
  float4 v = in[i];
  short4 o;
  o.x = f2bf(v.x); o.y = f2bf(v.y); o.z = f2bf(v.z); o.w = f2bf(v.w);
  outp[i] = o;
}

// ---------------- weight transpose+cast: [e][R][C] f32 -> [e][C][R] bf16 ----------------
__global__ void transpose_cast_kernel(const float* __restrict__ in, short* __restrict__ outp,
                                      int R, int C) {
  __shared__ float tile[32][33];
  int e = blockIdx.z;
  int c0 = blockIdx.x * 32, r0 = blockIdx.y * 32;
  const float* src = in + (size_t)e * R * C;
  short* dst = outp + (size_t)e * R * C;
  int tx = threadIdx.x, ty = threadIdx.y;
  for (int yy = ty; yy < 32; yy += 8)
    tile[yy][tx] = src[(size_t)(r0 + yy) * C + c0 + tx];
  __syncthreads();
  for (int yy = ty; yy < 32; yy += 8)
    dst[(size_t)(c0 + yy) * R + r0 + tx] = f2bf(tile[tx][yy]);
}

// ---------------- gate: scores, top-2, softmax, routing lists ----------------
__global__ void gate_kernel(const float* __restrict__ x, const float* __restrict__ gw,
                            int* __restrict__ cnt, int* __restrict__ tok,
                            float* __restrict__ wgt) {
  int wid = threadIdx.x >> 6;
  int lane = threadIdx.x & 63;
  int t = blockIdx.x * 4 + wid;
  if (t >= T_TOK) return;
  float s[N_EXP];
#pragma unroll
  for (int e = 0; e < N_EXP; e++) s[e] = 0.f;
  for (int d = lane; d < D_EMB; d += 64) {
    float xv = x[t * D_EMB + d];
#pragma unroll
    for (int e = 0; e < N_EXP; e++) s[e] += xv * gw[d * N_EXP + e];
  }
#pragma unroll
  for (int e = 0; e < N_EXP; e++) {
#pragma unroll
    for (int off = 32; off > 0; off >>= 1) s[e] += __shfl_xor(s[e], off, 64);
  }
  if (lane == 0) {
    int e0 = 0;
#pragma unroll
    for (int e = 1; e < N_EXP; e++) if (s[e] > s[e0]) e0 = e;
    int e1 = -1;
#pragma unroll
    for (int e = 0; e < N_EXP; e++) {
      if (e == e0) continue;
      if (e1 < 0 || s[e] > s[e1]) e1 = e;
    }
    float p1 = __expf(s[e1] - s[e0]);
    float inv = 1.f / (1.f + p1);
    float w0 = inv, w1 = p1 * inv;
    int p = atomicAdd(&cnt[e0], 1);
    tok[e0 * T_TOK + p] = t; wgt[e0 * T_TOK + p] = w0;
    p = atomicAdd(&cnt[e1], 1);
    tok[e1 * T_TOK + p] = t; wgt[e1 * T_TOK + p] = w1;
  }
}

// ---------------- exclusive prefix sum over 8 counters ----------------
__global__ void offs_kernel(const int* __restrict__ cnt, int* __restrict__ offs) {
  int o = 0;
  for (int e = 0; e < N_EXP; e++) { offs[e] = o; o += cnt[e]; }
}

// ---------------- FC: h[row] = gelu( xb[tok] @ wfcT[e]^T ), grouped over experts ----------------
__global__ __launch_bounds__(256, 2)
void fc_kernel(const short* __restrict__ xb,     // bf16 [4096][768]
               const short* __restrict__ wfcT,   // bf16 [8][3072][768]  (n-major, k-contig)
               const int* __restrict__ tok,
               const int* __restrict__ cnt,
               const int* __restrict__ offs,
               short* __restrict__ h) {          // bf16 [8192][3072]
  const int COLT = DFF / 128;   // 24
  const int ROWT = T_TOK / 128; // 32
  int bid = blockIdx.x;
  int e = bid / (ROWT * COLT);
  int rem = bid % (ROWT * COLT);
  int rt = rem / COLT;
  int ct = rem % COLT;
  int ne = cnt[e];
  if (rt * 128 >= ne) return;
  int base = offs[e];

  __shared__ __align__(16) short As[128 * 32];
  __shared__ __align__(16) short Bs[128 * 32];

  int tid = threadIdx.x;
  int lane = tid & 63;
  int wid = tid >> 6;

  // staging: seg in [0,512), row = seg>>2, physical 16B-slot p = seg&3 holds logical
  // k-chunk q = p ^ (row&3)   (XOR swizzle, applied identically on the read side)
  const short* aptr[2];
  const short* bptr[2];
  short* lA[2];
  short* lB[2];
#pragma unroll
  for (int i = 0; i < 2; i++) {
    int seg = tid + i * 256;
    int row = seg >> 2;
    int p = seg & 3;
    int q = p ^ (row & 3);
    int r = rt * 128 + row;
    if (r >= ne) r = ne - 1;
    int t = tok[e * T_TOK + r];
    aptr[i] = xb + (size_t)t * D_EMB + q * 8;
    bptr[i] = wfcT + ((size_t)e * DFF + ct * 128 + row) * D_EMB + q * 8;
    lA[i] = &As[seg * 8];
    lB[i] = &Bs[seg * 8];
  }

  f32x4 acc[4][4];
#pragma unroll
  for (int m = 0; m < 4; m++)
#pragma unroll
    for (int n = 0; n < 4; n++) acc[m][n] = (f32x4){0.f, 0.f, 0.f, 0.f};

  int wr = (wid >> 1) * 64, wc = (wid & 1) * 64;

  for (int k0 = 0; k0 < D_EMB; k0 += 32) {
#pragma unroll
    for (int i = 0; i < 2; i++) {
      gload16(aptr[i] + k0, lA[i]);
      gload16(bptr[i] + k0, lB[i]);
    }
    asm volatile("s_waitcnt vmcnt(0)" ::: "memory");
    __syncthreads();

    bf16x8 af[4], bfv[4];
#pragma unroll
    for (int m = 0; m < 4; m++) {
      int row = wr + m * 16 + (lane & 15);
      af[m] = *(const bf16x8*)&As[row * 32 + (((lane >> 4)) ^ (row & 3)) * 8];
    }
#pragma unroll
    for (int n = 0; n < 4; n++) {
      int row = wc + n * 16 + (lane & 15);
      bfv[n] = *(const bf16x8*)&Bs[row * 32 + (((lane >> 4)) ^ (row & 3)) * 8];
    }
#pragma unroll
    for (int m = 0; m < 4; m++)
#pragma unroll
      for (int n = 0; n < 4; n++)
        acc[m][n] = __builtin_amdgcn_mfma_f32_16x16x32_bf16(af[m], bfv[n], acc[m][n], 0, 0, 0);
    __syncthreads();
  }

  int colbase = ct * 128 + wc;
#pragma unroll
  for (int m = 0; m < 4; m++) {
#pragma unroll
    for (int j = 0; j < 4; j++) {
      int rloc = rt * 128 + wr + m * 16 + ((lane >> 4) << 2) + j;
      if (rloc < ne) {
        size_t hrow = (size_t)(base + rloc) * DFF;
#pragma unroll
        for (int n = 0; n < 4; n++) {
          float v = acc[m][n][j];
          float g = 0.5f * v * (1.0f + erff(v * 0.70710678118f));
          h[hrow + colbase + n * 16 + (lane & 15)] = f2bf(g);
        }
      }
    }
  }
}

// ---------------- PROJ: out[tok] += w * ( h[row] @ wpjT[e]^T ), grouped ----------------
__global__ __launch_bounds__(256, 2)
void proj_kernel(const short* __restrict__ h,     // bf16 [8192][3072]
                 const short* __restrict__ wpjT,  // bf16 [8][768][3072] (n-major, k-contig)
                 const int* __restrict__ tok,
                 const float* __restrict__ wgt,
                 const int* __restrict__ cnt,
                 const int* __restrict__ offs,
                 float* __restrict__ out) {       // f32 [4096][768]
  const int COLT = D_EMB / 128; // 6
  const int ROWT = T_TOK / 128; // 32
  int bid = blockIdx.x;
  int e = bid / (ROWT * COLT);
  int rem = bid % (ROWT * COLT);
  int rt = rem / COLT;
  int ct = rem % COLT;
  int ne = cnt[e];
  if (rt * 128 >= ne) return;
  int base = offs[e];

  __shared__ __align__(16) short As[128 * 32];
  __shared__ __align__(16) short Bs[128 * 32];

  int tid = threadIdx.x;
  int lane = tid & 63;
  int wid = tid >> 6;

  const short* aptr[2];
  const short* bptr[2];
  short* lA[2];
  short* lB[2];
#pragma unroll
  for (int i = 0; i < 2; i++) {
    int seg = tid + i * 256;
    int row = seg >> 2;
    int p = seg & 3;
    int q = p ^ (row & 3);
    int r = rt * 128 + row;
    if (r >= ne) r = ne - 1;
    aptr[i] = h + (size_t)(base + r) * DFF + q * 8;
    bptr[i] = wpjT + ((size_t)e * D_EMB + ct * 128 + row) * DFF + q * 8;
    lA[i] = &As[seg * 8];
    lB[i] = &Bs[seg * 8];
  }

  f32x4 acc[4][4];
#pragma unroll
  for (int m = 0; m < 4; m++)
#pragma unroll
    for (int n = 0; n < 4; n++) acc[m][n] = (f32x4){0.f, 0.f, 0.f, 0.f};

  int wr = (wid >> 1) * 64, wc = (wid & 1) * 64;

  for (int k0 = 0; k0 < DFF; k0 += 32) {
#pragma unroll
    for (int i = 0; i < 2; i++) {
      gload16(aptr[i] + k0, lA[i]);
      gload16(bptr[i] + k0, lB[i]);
    }
    asm volatile("s_waitcnt vmcnt(0)" ::: "memory");
    __syncthreads();

    bf16x8 af[4], bfv[4];
#pragma unroll
    for (int m = 0; m < 4; m++) {
      int row = wr + m * 16 + (lane & 15);
      af[m] = *(const bf16x8*)&As[row * 32 + (((lane >> 4)) ^ (row & 3)) * 8];
    }
#pragma unroll
    for (int n = 0; n < 4; n++) {
      int row = wc + n * 16 + (lane & 15);
      bfv[n] = *(const bf16x8*)&Bs[row * 32 + (((lane >> 4)) ^ (row & 3)) * 8];
    }
#pragma unroll
    for (int m = 0; m < 4; m++)
#pragma unroll
      for (int n = 0; n < 4; n++)
        acc[m][n] = __builtin_amdgcn_mfma_f32_16x16x32_bf16(af[m], bfv[n], acc[m][n], 0, 0, 0);
    __syncthreads();
  }

  int colbase = ct * 128 + wc;
#pragma unroll
  for (int m = 0; m < 4; m++) {
#pragma unroll
    for (int j = 0; j < 4; j++) {
      int rloc = rt * 128 + wr + m * 16 + ((lane >> 4) << 2) + j;
      if (rloc < ne) {
        int t = tok[e * T_TOK + rloc];
        float w = wgt[e * T_TOK + rloc];
        float* orow = out + (size_t)t * D_EMB + colbase + (lane & 15);
#pragma unroll
        for (int n = 0; n < 4; n++)
          atomicAdd(orow + n * 16, w * acc[m][n][j]);
      }
    }
  }
}

extern "C" void kernel_launch(void* const* d_in, const int* in_sizes, int n_in,
                              void* d_out, int out_size, void* d_ws, size_t ws_size,
                              hipStream_t stream) {
  const float* x   = (const float*)d_in[0];
  const float* gw  = (const float*)d_in[1];
  const float* wfc = (const float*)d_in[2];
  const float* wpj = (const float*)d_in[3];
  float* out = (float*)d_out;

  char* ws = (char*)d_ws;
  const size_t SZ_XB   = (size_t)T_TOK * D_EMB * 2;          // 6,291,456
  const size_t SZ_W    = (size_t)N_EXP * D_EMB * DFF * 2;    // 37,748,736
  const size_t SZ_H    = (size_t)2 * T_TOK * DFF * 2;        // 50,331,648
  short* xb   = (short*)(ws);
  short* wfcT = (short*)(ws + SZ_XB);
  short* wpjT = (short*)(ws + SZ_XB + SZ_W);
  short* h    = (short*)(ws + SZ_XB + 2 * SZ_W);
  char* p2    = ws + SZ_XB + 2 * SZ_W + SZ_H;
  int*   tok  = (int*)(p2);
  float* wgt  = (float*)(p2 + (size_t)N_EXP * T_TOK * 4);
  int*   cnt  = (int*)(p2 + (size_t)N_EXP * T_TOK * 8);
  int*   offs = (int*)(p2 + (size_t)N_EXP * T_TOK * 8 + 64);

  int n4 = out_size / 4;
  zero_init_kernel<<<2048, 256, 0, stream>>>((float4*)out, n4, cnt);
  cast_x_kernel<<<(T_TOK * D_EMB / 4 + 255) / 256, 256, 0, stream>>>(
      (const float4*)x, (short4*)xb, T_TOK * D_EMB / 4);
  dim3 tb(32, 8);
  transpose_cast_kernel<<<dim3(DFF / 32, D_EMB / 32, N_EXP), tb, 0, stream>>>(wfc, wfcT, D_EMB, DFF);
  transpose_cast_kernel<<<dim3(D_EMB / 32, DFF / 32, N_EXP), tb, 0, stream>>>(wpj, wpjT, DFF, D_EMB);
  gate_kernel<<<T_TOK / 4, 256, 0, stream>>>(x, gw, cnt, tok, wgt);
  offs_kernel<<<1, 1, 0, stream>>>(cnt, offs);
  fc_kernel<<<N_EXP * (T_TOK / 128) * (DFF / 128), 256, 0, stream>>>(xb, wfcT, tok, cnt, offs, h);
  proj_kernel<<<N_EXP * (T_TOK / 128) * (D_EMB / 128), 256, 0, stream>>>(h, wpjT, tok, wgt, cnt, offs, out);
}

// Round 3
// 315.253 us; speedup vs baseline: 1.2580x; 1.2580x over previous
//
#include <hip/hip_runtime.h>
#include <hip/hip_bf16.h>
#include <math.h>

#define T_TOK 4096
#define D_EMB 768
#define DFF   3072
#define N_EXP 8
#define MAXT  72   // max row-tiles: 8192/128 + 8 partials

typedef __attribute__((ext_vector_type(8))) short bf16x8;
typedef __attribute__((ext_vector_type(4))) float f32x4;

typedef __attribute__((address_space(3))) unsigned int lds_u32_t;
typedef __attribute__((address_space(1))) unsigned int glob_u32_t;

__device__ __forceinline__ void gload16(const void* g, void* l) {
  __builtin_amdgcn_global_load_lds((const glob_u32_t*)g, (lds_u32_t*)l, 16, 0, 0);
}

__device__ __forceinline__ short f2bf(float f) {
  union { __hip_bfloat16 b; short s; } u;
  u.b = __float2bfloat16(f);
  return u.s;
}

// ---------------- zero out + counters ----------------
__global__ void zero_init_kernel(float4* __restrict__ out4, int n4, int* __restrict__ cnt) {
  int i = blockIdx.x * blockDim.x + threadIdx.x;
  if (i < N_EXP) cnt[i] = 0;
  float4 z; z.x = z.y = z.z = z.w = 0.f;
  for (int j = i; j < n4; j += gridDim.x * blockDim.x) out4[j] = z;
}

// ---------------- x fp32 -> bf16 ----------------
__global__ void cast_x_kernel(const float4* __restrict__ in, short4* __restrict__ outp, int n4) {
  int i = blockIdx.x * blockDim.x + threadIdx.x;
  if (i >= n4) return;
  float4 v = in[i];
  short4 o;
  o.x = f2bf(v.x); o.y = f2bf(v.y); o.z = f2bf(v.z); o.w = f2bf(v.w);
  outp[i] = o;
}

// ---------------- weight transpose+cast: [e][R][C] f32 -> [e][C][R] bf16 ----------------
// 64x64 tiles, float4 loads, short4 coalesced stores.
__global__ void transpose_cast_kernel(const float* __restrict__ in, short* __restrict__ outp,
                                      int R, int C) {
  __shared__ float tile[64][65];
  int e = blockIdx.z;
  int c0 = blockIdx.x * 64, r0 = blockIdx.y * 64;
  const float* src = in + (size_t)e * R * C;
  short* dst = outp + (size_t)e * R * C;
  int tid = threadIdx.x;
#pragma unroll
  for (int it = 0; it < 4; ++it) {
    int idx = tid + it * 256;
    int r = idx >> 4;          // 0..63
    int c4 = idx & 15;         // 0..15
    float4 v = *(const float4*)&src[(size_t)(r0 + r) * C + c0 + c4 * 4];
    tile[r][c4 * 4 + 0] = v.x; tile[r][c4 * 4 + 1] = v.y;
    tile[r][c4 * 4 + 2] = v.z; tile[r][c4 * 4 + 3] = v.w;
  }
  __syncthreads();
#pragma unroll
  for (int it = 0; it < 4; ++it) {
    int idx = tid + it * 256;
    int c = idx >> 4;          // 0..63
    int rr = idx & 15;         // 0..15
    short4 o;
    o.x = f2bf(tile[rr * 4 + 0][c]);
    o.y = f2bf(tile[rr * 4 + 1][c]);
    o.z = f2bf(tile[rr * 4 + 2][c]);
    o.w = f2bf(tile[rr * 4 + 3][c]);
    *(short4*)&dst[(size_t)(c0 + c) * R + r0 + rr * 4] = o;
  }
}

// ---------------- gate: scores, top-2, softmax, routing lists ----------------
__global__ void gate_kernel(const float* __restrict__ x, const float* __restrict__ gw,
                            int* __restrict__ cnt, int* __restrict__ tok,
                            float* __restrict__ wgt) {
  int wid = threadIdx.x >> 6;
  int lane = threadIdx.x & 63;
  int t = blockIdx.x * 4 + wid;
  if (t >= T_TOK) return;
  float s[N_EXP];
#pragma unroll
  for (int e = 0; e < N_EXP; e++) s[e] = 0.f;
  for (int d = lane; d < D_EMB; d += 64) {
    float xv = x[t * D_EMB + d];
#pragma unroll
    for (int e = 0; e < N_EXP; e++) s[e] += xv * gw[d * N_EXP + e];
  }
#pragma unroll
  for (int e = 0; e < N_EXP; e++) {
#pragma unroll
    for (int off = 32; off > 0; off >>= 1) s[e] += __shfl_xor(s[e], off, 64);
  }
  if (lane == 0) {
    int e0 = 0;
#pragma unroll
    for (int e = 1; e < N_EXP; e++) if (s[e] > s[e0]) e0 = e;
    int e1 = -1;
#pragma unroll
    for (int e = 0; e < N_EXP; e++) {
      if (e == e0) continue;
      if (e1 < 0 || s[e] > s[e1]) e1 = e;
    }
    float p1 = __expf(s[e1] - s[e0]);
    float inv = 1.f / (1.f + p1);
    float w0 = inv, w1 = p1 * inv;
    int p = atomicAdd(&cnt[e0], 1);
    tok[e0 * T_TOK + p] = t; wgt[e0 * T_TOK + p] = w0;
    p = atomicAdd(&cnt[e1], 1);
    tok[e1 * T_TOK + p] = t; wgt[e1 * T_TOK + p] = w1;
  }
}

// ---------------- plan: offsets + compacted (expert, row-tile) list ----------------
__global__ void plan_kernel(const int* __restrict__ cnt, int* __restrict__ offs,
                            int* __restrict__ tile_e, int* __restrict__ tile_rt,
                            int* __restrict__ ntiles) {
  if (threadIdx.x != 0 || blockIdx.x != 0) return;
  int o = 0, nt = 0;
  for (int e = 0; e < N_EXP; e++) {
    offs[e] = o;
    int tc = (cnt[e] + 127) >> 7;
    for (int i = 0; i < tc; i++) { tile_e[nt] = e; tile_rt[nt] = i; nt++; }
    o += cnt[e];
  }
  *ntiles = nt;
}

// ---------------- grouped GEMM, 128x128 tile, BK=64, dbuf LDS, 2-phase ----------------
// EPI=0: FC   — A-row via tok[], epilogue gelu -> hout (bf16, stride NDIM)
// EPI=1: PROJ — A-row = base+r,  epilogue atomicAdd(w * acc) -> fout (f32, stride NDIM)
template<int KDIM, int NDIM, int EPI>
__global__ __launch_bounds__(256, 2)
void moe_gemm(const short* __restrict__ A, const short* __restrict__ Bw,
              const int* __restrict__ tok, const float* __restrict__ wgt,
              const int* __restrict__ cnt, const int* __restrict__ offs,
              const int* __restrict__ tile_e, const int* __restrict__ tile_rt,
              const int* __restrict__ ntiles,
              short* __restrict__ hout, float* __restrict__ fout) {
  const int COLT = NDIM / 128;
  // bijective XCD swizzle (gridDim.x % 8 == 0)
  int nwg = gridDim.x;
  int cpx = nwg >> 3;
  int logical = (blockIdx.x & 7) * cpx + (blockIdx.x >> 3);
  int tile = logical / COLT, ct = logical % COLT;
  if (tile >= *ntiles) return;
  int e = tile_e[tile], rt = tile_rt[tile];
  int ne = cnt[e];
  int base = offs[e];

  __shared__ __align__(16) short As[2][128 * 64];
  __shared__ __align__(16) short Bs[2][128 * 64];

  int tid = threadIdx.x;
  int lane = tid & 63;
  int wid = tid >> 6;

  // staging map: seg in [0,1024), row = seg>>3, physical slot p = seg&7 holds
  // logical 16B k-chunk q = p ^ (row&7); read side applies the same XOR.
  const short* aptr[4];
  const short* bptr[4];
  int lofs[4];
#pragma unroll
  for (int i = 0; i < 4; i++) {
    int seg = tid + i * 256;
    int row = seg >> 3;
    int p = seg & 7;
    int q = p ^ (row & 7);
    int r = rt * 128 + row;
    if (r >= ne) r = ne - 1;
    size_t ga = (EPI == 0) ? (size_t)tok[e * T_TOK + r] : (size_t)(base + r);
    aptr[i] = A + ga * KDIM + q * 8;
    bptr[i] = Bw + ((size_t)e * NDIM + ct * 128 + row) * KDIM + q * 8;
    lofs[i] = seg * 8;
  }

  f32x4 acc[4][4];
#pragma unroll
  for (int m = 0; m < 4; m++)
#pragma unroll
    for (int n = 0; n < 4; n++) acc[m][n] = (f32x4){0.f, 0.f, 0.f, 0.f};

  int wr = (wid >> 1) * 64, wc = (wid & 1) * 64;

  // prologue: stage tile 0 into buf 0
#pragma unroll
  for (int i = 0; i < 4; i++) {
    gload16(aptr[i], &As[0][lofs[i]]);
    gload16(bptr[i], &Bs[0][lofs[i]]);
  }
  __syncthreads();

  const int NKT = KDIM / 64;
  int cur = 0;
  for (int kt = 0; kt < NKT; ++kt) {
    if (kt + 1 < NKT) {
      int k0 = (kt + 1) * 64;
#pragma unroll
      for (int i = 0; i < 4; i++) {
        gload16(aptr[i] + k0, &As[cur ^ 1][lofs[i]]);
        gload16(bptr[i] + k0, &Bs[cur ^ 1][lofs[i]]);
      }
    }
    bf16x8 af[2][4], bv[2][4];
#pragma unroll
    for (int kk = 0; kk < 2; kk++) {
      int cb = kk * 4 + (lane >> 4);
#pragma unroll
      for (int m = 0; m < 4; m++) {
        int row = wr + m * 16 + (lane & 15);
        af[kk][m] = *(const bf16x8*)&As[cur][row * 64 + (cb ^ (row & 7)) * 8];
      }
#pragma unroll
      for (int n = 0; n < 4; n++) {
        int row = wc + n * 16 + (lane & 15);
        bv[kk][n] = *(const bf16x8*)&Bs[cur][row * 64 + (cb ^ (row & 7)) * 8];
      }
    }
#pragma unroll
    for (int kk = 0; kk < 2; kk++)
#pragma unroll
      for (int m = 0; m < 4; m++)
#pragma unroll
        for (int n = 0; n < 4; n++)
          acc[m][n] = __builtin_amdgcn_mfma_f32_16x16x32_bf16(af[kk][m], bv[kk][n], acc[m][n], 0, 0, 0);
    __syncthreads();  // implicit vmcnt(0) drain: next tile staged, all reads done
    cur ^= 1;
  }

  int colbase = ct * 128 + wc;
#pragma unroll
  for (int m = 0; m < 4; m++) {
#pragma unroll
    for (int j = 0; j < 4; j++) {
      int rloc = rt * 128 + wr + m * 16 + ((lane >> 4) << 2) + j;
      if (rloc < ne) {
        if (EPI == 0) {
          size_t hrow = (size_t)(base + rloc) * NDIM;
#pragma unroll
          for (int n = 0; n < 4; n++) {
            float v = acc[m][n][j];
            float g = 0.5f * v * (1.0f + erff(v * 0.70710678118f));
            hout[hrow + colbase + n * 16 + (lane & 15)] = f2bf(g);
          }
        } else {
          int t = tok[e * T_TOK + rloc];
          float w = wgt[e * T_TOK + rloc];
          float* orow = fout + (size_t)t * NDIM + colbase + (lane & 15);
#pragma unroll
          for (int n = 0; n < 4; n++)
            atomicAdd(orow + n * 16, w * acc[m][n][j]);
        }
      }
    }
  }
}

extern "C" void kernel_launch(void* const* d_in, const int* in_sizes, int n_in,
                              void* d_out, int out_size, void* d_ws, size_t ws_size,
                              hipStream_t stream) {
  const float* x   = (const float*)d_in[0];
  const float* gw  = (const float*)d_in[1];
  const float* wfc = (const float*)d_in[2];
  const float* wpj = (const float*)d_in[3];
  float* out = (float*)d_out;

  char* ws = (char*)d_ws;
  const size_t SZ_XB = (size_t)T_TOK * D_EMB * 2;
  const size_t SZ_W  = (size_t)N_EXP * D_EMB * DFF * 2;
  const size_t SZ_H  = (size_t)2 * T_TOK * DFF * 2;
  short* xb   = (short*)(ws);
  short* wfcT = (short*)(ws + SZ_XB);
  short* wpjT = (short*)(ws + SZ_XB + SZ_W);
  short* h    = (short*)(ws + SZ_XB + 2 * SZ_W);
  char* p2    = ws + SZ_XB + 2 * SZ_W + SZ_H;
  int*   tok  = (int*)(p2);
  float* wgt  = (float*)(p2 + (size_t)N_EXP * T_TOK * 4);
  char* p3    = p2 + (size_t)N_EXP * T_TOK * 8;
  int*   cnt     = (int*)(p3);
  int*   offs    = (int*)(p3 + 64);
  int*   tile_e  = (int*)(p3 + 128);
  int*   tile_rt = (int*)(p3 + 128 + 512);
  int*   ntiles  = (int*)(p3 + 128 + 1024);

  int n4 = out_size / 4;
  zero_init_kernel<<<2048, 256, 0, stream>>>((float4*)out, n4, cnt);
  cast_x_kernel<<<(T_TOK * D_EMB / 4 + 255) / 256, 256, 0, stream>>>(
      (const float4*)x, (short4*)xb, T_TOK * D_EMB / 4);
  transpose_cast_kernel<<<dim3(DFF / 64, D_EMB / 64, N_EXP), 256, 0, stream>>>(wfc, wfcT, D_EMB, DFF);
  transpose_cast_kernel<<<dim3(D_EMB / 64, DFF / 64, N_EXP), 256, 0, stream>>>(wpj, wpjT, DFF, D_EMB);
  gate_kernel<<<T_TOK / 4, 256, 0, stream>>>(x, gw, cnt, tok, wgt);
  plan_kernel<<<1, 1, 0, stream>>>(cnt, offs, tile_e, tile_rt, ntiles);
  // FC: K=768, N=3072 ; PROJ: K=3072, N=768
  moe_gemm<D_EMB, DFF, 0><<<MAXT * (DFF / 128), 256, 0, stream>>>(
      xb, wfcT, tok, wgt, cnt, offs, tile_e, tile_rt, ntiles, h, nullptr);
  moe_gemm<DFF, D_EMB, 1><<<MAXT * (D_EMB / 128), 256, 0, stream>>>(
      h, wpjT, tok, wgt, cnt, offs, tile_e, tile_rt, ntiles, nullptr, out);
}

// Round 6
// 235.856 us; speedup vs baseline: 1.6815x; 1.3366x over previous
//
#include <hip/hip_runtime.h>
#include <hip/hip_bf16.h>
#include <math.h>

#define T_TOK 4096
#define D_EMB 768
#define DFF   3072
#define N_EXP 8
#define MAXT  72   // max row-tiles: 8192/128 + 8 partials
#define CNTS  16   // cnt padding stride (ints) -> one 64B line per expert

typedef __attribute__((ext_vector_type(8))) short bf16x8;
typedef __attribute__((ext_vector_type(4))) float f32x4;

typedef __attribute__((address_space(3))) unsigned int lds_u32_t;
typedef __attribute__((address_space(1))) unsigned int glob_u32_t;

__device__ __forceinline__ void gload16(const void* g, void* l) {
  __builtin_amdgcn_global_load_lds((const glob_u32_t*)g, (lds_u32_t*)l, 16, 0, 0);
}

__device__ __forceinline__ short f2bf(float f) {
  union { __hip_bfloat16 b; short s; } u;
  u.b = __float2bfloat16(f);
  return u.s;
}

// ---------------- zero out + counters ----------------
__global__ void zero_init_kernel(float4* __restrict__ out4, int n4, int* __restrict__ cnt) {
  int i = blockIdx.x * blockDim.x + threadIdx.x;
  if (i < N_EXP * CNTS) cnt[i] = 0;
  float4 z; z.x = z.y = z.z = z.w = 0.f;
  for (int j = i; j < n4; j += gridDim.x * blockDim.x) out4[j] = z;
}

// ---------------- x fp32 -> bf16 ----------------
__global__ void cast_x_kernel(const float4* __restrict__ in, short4* __restrict__ outp, int n4) {
  int i = blockIdx.x * blockDim.x + threadIdx.x;
  if (i >= n4) return;
  float4 v = in[i];
  short4 o;
  o.x = f2bf(v.x); o.y = f2bf(v.y); o.z = f2bf(v.z); o.w = f2bf(v.w);
  outp[i] = o;
}

// ---------------- weight transpose+cast: [e][R][C] f32 -> [e][C][R] bf16 ----------------
__global__ void transpose_cast_kernel(const float* __restrict__ in, short* __restrict__ outp,
                                      int R, int C) {
  __shared__ float tile[64][65];
  int e = blockIdx.z;
  int c0 = blockIdx.x * 64, r0 = blockIdx.y * 64;
  const float* src = in + (size_t)e * R * C;
  short* dst = outp + (size_t)e * R * C;
  int tid = threadIdx.x;
#pragma unroll
  for (int it = 0; it < 4; ++it) {
    int idx = tid + it * 256;
    int r = idx >> 4;
    int c4 = idx & 15;
    float4 v = *(const float4*)&src[(size_t)(r0 + r) * C + c0 + c4 * 4];
    tile[r][c4 * 4 + 0] = v.x; tile[r][c4 * 4 + 1] = v.y;
    tile[r][c4 * 4 + 2] = v.z; tile[r][c4 * 4 + 3] = v.w;
  }
  __syncthreads();
#pragma unroll
  for (int it = 0; it < 4; ++it) {
    int idx = tid + it * 256;
    int c = idx >> 4;
    int rr = idx & 15;
    short4 o;
    o.x = f2bf(tile[rr * 4 + 0][c]);
    o.y = f2bf(tile[rr * 4 + 1][c]);
    o.z = f2bf(tile[rr * 4 + 2][c]);
    o.w = f2bf(tile[rr * 4 + 3][c]);
    *(short4*)&dst[(size_t)(c0 + c) * R + r0 + rr * 4] = o;
  }
}

// ---------------- gate: 16 tokens/block, LDS-aggregated routing ----------------
__global__ __launch_bounds__(256)
void gate_kernel(const float* __restrict__ x, const float* __restrict__ gw,
                 int* __restrict__ cnt, int* __restrict__ tok,
                 float* __restrict__ wgt) {
  __shared__ int lcnt[N_EXP];
  __shared__ int gbase[N_EXP];
  __shared__ int le[32];
  __shared__ float lw[32];
  __shared__ int lpos[32];
  int tid = threadIdx.x, lane = tid & 63, wid = tid >> 6;
  if (tid < N_EXP) lcnt[tid] = 0;
  __syncthreads();

#pragma unroll
  for (int i = 0; i < 4; i++) {
    int t = blockIdx.x * 16 + wid * 4 + i;
    float s[N_EXP];
#pragma unroll
    for (int e = 0; e < N_EXP; e++) s[e] = 0.f;
#pragma unroll
    for (int dd = 0; dd < D_EMB / 64; dd++) {
      int d = dd * 64 + lane;
      float xv = x[(size_t)t * D_EMB + d];
#pragma unroll
      for (int e = 0; e < N_EXP; e++) s[e] += xv * gw[d * N_EXP + e];
    }
#pragma unroll
    for (int e = 0; e < N_EXP; e++) {
#pragma unroll
      for (int off = 32; off > 0; off >>= 1) s[e] += __shfl_xor(s[e], off, 64);
    }
    if (lane == 0) {
      int e0 = 0;
#pragma unroll
      for (int e = 1; e < N_EXP; e++) if (s[e] > s[e0]) e0 = e;
      int e1 = -1;
#pragma unroll
      for (int e = 0; e < N_EXP; e++) {
        if (e == e0) continue;
        if (e1 < 0 || s[e] > s[e1]) e1 = e;
      }
      float p1 = __expf(s[e1] - s[e0]);
      float inv = 1.f / (1.f + p1);
      int idx = (wid * 4 + i) * 2;
      le[idx] = e0; lw[idx] = inv;           lpos[idx] = atomicAdd(&lcnt[e0], 1);
      le[idx + 1] = e1; lw[idx + 1] = p1 * inv; lpos[idx + 1] = atomicAdd(&lcnt[e1], 1);
    }
  }
  __syncthreads();
  if (tid < N_EXP) gbase[tid] = atomicAdd(&cnt[tid * CNTS], lcnt[tid]);
  __syncthreads();
  if (tid < 32) {
    int e = le[tid];
    int t = blockIdx.x * 16 + (tid >> 1);
    int p = gbase[e] + lpos[tid];
    tok[e * T_TOK + p] = t;
    wgt[e * T_TOK + p] = lw[tid];
  }
}

// ---------------- plan: offsets + compacted (expert, row-tile) list ----------------
__global__ void plan_kernel(const int* __restrict__ cnt, int* __restrict__ offs,
                            int* __restrict__ tile_e, int* __restrict__ tile_rt,
                            int* __restrict__ ntiles) {
  if (threadIdx.x != 0 || blockIdx.x != 0) return;
  int o = 0, nt = 0;
  for (int e = 0; e < N_EXP; e++) {
    offs[e] = o;
    int tc = (cnt[e * CNTS] + 127) >> 7;
    for (int i = 0; i < tc; i++) { tile_e[nt] = e; tile_rt[nt] = i; nt++; }
    o += cnt[e * CNTS];
  }
  *ntiles = nt;
}

// ---------------- grouped GEMM, 128x128 tile, BK=64, dbuf LDS, 2-phase ----------------
template<int KDIM, int NDIM, int EPI>
__global__ __launch_bounds__(256, 2)
void moe_gemm(const short* __restrict__ A, const short* __restrict__ Bw,
              const int* __restrict__ tok, const float* __restrict__ wgt,
              const int* __restrict__ cnt, const int* __restrict__ offs,
              const int* __restrict__ tile_e, const int* __restrict__ tile_rt,
              const int* __restrict__ ntiles,
              short* __restrict__ hout, float* __restrict__ fout) {
  const int COLT = NDIM / 128;
  int nwg = gridDim.x;
  int cpx = nwg >> 3;
  int logical = (blockIdx.x & 7) * cpx + (blockIdx.x >> 3);
  int tile = logical / COLT, ct = logical % COLT;
  if (tile >= *ntiles) return;
  int e = tile_e[tile], rt = tile_rt[tile];
  int ne = cnt[e * CNTS];
  int base = offs[e];

  __shared__ __align__(16) short As[2][128 * 64];
  __shared__ __align__(16) short Bs[2][128 * 64];

  int tid = threadIdx.x;
  int lane = tid & 63;
  int wid = tid >> 6;

  const short* aptr[4];
  const short* bptr[4];
  int lofs[4];
#pragma unroll
  for (int i = 0; i < 4; i++) {
    int seg = tid + i * 256;
    int row = seg >> 3;
    int p = seg & 7;
    int q = p ^ (row & 7);
    int r = rt * 128 + row;
    if (r >= ne) r = ne - 1;
    size_t ga = (EPI == 0) ? (size_t)tok[e * T_TOK + r] : (size_t)(base + r);
    aptr[i] = A + ga * KDIM + q * 8;
    bptr[i] = Bw + ((size_t)e * NDIM + ct * 128 + row) * KDIM + q * 8;
    lofs[i] = seg * 8;
  }

  f32x4 acc[4][4];
#pragma unroll
  for (int m = 0; m < 4; m++)
#pragma unroll
    for (int n = 0; n < 4; n++) acc[m][n] = (f32x4){0.f, 0.f, 0.f, 0.f};

  int wr = (wid >> 1) * 64, wc = (wid & 1) * 64;

#pragma unroll
  for (int i = 0; i < 4; i++) {
    gload16(aptr[i], &As[0][lofs[i]]);
    gload16(bptr[i], &Bs[0][lofs[i]]);
  }
  __syncthreads();

  const int NKT = KDIM / 64;
  int cur = 0;
  for (int kt = 0; kt < NKT; ++kt) {
    if (kt + 1 < NKT) {
      int k0 = (kt + 1) * 64;
#pragma unroll
      for (int i = 0; i < 4; i++) {
        gload16(aptr[i] + k0, &As[cur ^ 1][lofs[i]]);
        gload16(bptr[i] + k0, &Bs[cur ^ 1][lofs[i]]);
      }
    }
    bf16x8 af[2][4], bv[2][4];
#pragma unroll
    for (int kk = 0; kk < 2; kk++) {
      int cb = kk * 4 + (lane >> 4);
#pragma unroll
      for (int m = 0; m < 4; m++) {
        int row = wr + m * 16 + (lane & 15);
        af[kk][m] = *(const bf16x8*)&As[cur][row * 64 + (cb ^ (row & 7)) * 8];
      }
#pragma unroll
      for (int n = 0; n < 4; n++) {
        int row = wc + n * 16 + (lane & 15);
        bv[kk][n] = *(const bf16x8*)&Bs[cur][row * 64 + (cb ^ (row & 7)) * 8];
      }
    }
#pragma unroll
    for (int kk = 0; kk < 2; kk++)
#pragma unroll
      for (int m = 0; m < 4; m++)
#pragma unroll
        for (int n = 0; n < 4; n++)
          acc[m][n] = __builtin_amdgcn_mfma_f32_16x16x32_bf16(af[kk][m], bv[kk][n], acc[m][n], 0, 0, 0);
    __syncthreads();
    cur ^= 1;
  }

  int colbase = ct * 128 + wc;
#pragma unroll
  for (int m = 0; m < 4; m++) {
#pragma unroll
    for (int j = 0; j < 4; j++) {
      int rloc = rt * 128 + wr + m * 16 + ((lane >> 4) << 2) + j;
      if (rloc < ne) {
        if (EPI == 0) {
          size_t hrow = (size_t)(base + rloc) * NDIM;
#pragma unroll
          for (int n = 0; n < 4; n++) {
            float v = acc[m][n][j];
            float g = 0.5f * v * (1.0f + erff(v * 0.70710678118f));
            hout[hrow + colbase + n * 16 + (lane & 15)] = f2bf(g);
          }
        } else {
          int t = tok[e * T_TOK + rloc];
          float w = wgt[e * T_TOK + rloc];
          float* orow = fout + (size_t)t * NDIM + colbase + (lane & 15);
#pragma unroll
          for (int n = 0; n < 4; n++)
            atomicAdd(orow + n * 16, w * acc[m][n][j]);
        }
      }
    }
  }
}

extern "C" void kernel_launch(void* const* d_in, const int* in_sizes, int n_in,
                              void* d_out, int out_size, void* d_ws, size_t ws_size,
                              hipStream_t stream) {
  const float* x   = (const float*)d_in[0];
  const float* gw  = (const float*)d_in[1];
  const float* wfc = (const float*)d_in[2];
  const float* wpj = (const float*)d_in[3];
  float* out = (float*)d_out;

  char* ws = (char*)d_ws;
  const size_t SZ_XB = (size_t)T_TOK * D_EMB * 2;
  const size_t SZ_W  = (size_t)N_EXP * D_EMB * DFF * 2;
  const size_t SZ_H  = (size_t)2 * T_TOK * DFF * 2;
  short* xb   = (short*)(ws);
  short* wfcT = (short*)(ws + SZ_XB);
  short* wpjT = (short*)(ws + SZ_XB + SZ_W);
  short* h    = (short*)(ws + SZ_XB + 2 * SZ_W);
  char* p2    = ws + SZ_XB + 2 * SZ_W + SZ_H;
  int*   tok  = (int*)(p2);
  float* wgt  = (float*)(p2 + (size_t)N_EXP * T_TOK * 4);
  char* p3    = p2 + (size_t)N_EXP * T_TOK * 8;
  int*   cnt     = (int*)(p3);                     // padded: N_EXP*CNTS ints
  int*   offs    = (int*)(p3 + 1024);
  int*   tile_e  = (int*)(p3 + 1024 + 64);
  int*   tile_rt = (int*)(p3 + 1024 + 64 + 512);
  int*   ntiles  = (int*)(p3 + 1024 + 64 + 1024);

  int n4 = out_size / 4;
  zero_init_kernel<<<2048, 256, 0, stream>>>((float4*)out, n4, cnt);
  cast_x_kernel<<<(T_TOK * D_EMB / 4 + 255) / 256, 256, 0, stream>>>(
      (const float4*)x, (short4*)xb, T_TOK * D_EMB / 4);
  transpose_cast_kernel<<<dim3(DFF / 64, D_EMB / 64, N_EXP), 256, 0, stream>>>(wfc, wfcT, D_EMB, DFF);
  transpose_cast_kernel<<<dim3(D_EMB / 64, DFF / 64, N_EXP), 256, 0, stream>>>(wpj, wpjT, DFF, D_EMB);
  gate_kernel<<<T_TOK / 16, 256, 0, stream>>>(x, gw, cnt, tok, wgt);
  plan_kernel<<<1, 1, 0, stream>>>(cnt, offs, tile_e, tile_rt, ntiles);
  moe_gemm<D_EMB, DFF, 0><<<MAXT * (DFF / 128), 256, 0, stream>>>(
      xb, wfcT, tok, wgt, cnt, offs, tile_e, tile_rt, ntiles, h, nullptr);
  moe_gemm<DFF, D_EMB, 1><<<MAXT * (D_EMB / 128), 256, 0, stream>>>(
      h, wpjT, tok, wgt, cnt, offs, tile_e, tile_rt, ntiles, nullptr, out);
}